// Round 2
// baseline (1821.022 us; speedup 1.0000x reference)
//
#include <hip/hip_runtime.h>
#include <math.h>

#define NORB 256
#define NF 128
#define STRIDE 132        // padded column stride (floats); 132*4=528 B, 16B-aligned
#define BLOCK 256

// LDS layout (dynamic):
//   float At[NF*STRIDE]   column-major: At[j*STRIDE + i] = A[i][j]
//   float pivbuf[NF]
//   int   R[NF]
//   float s_f[8]          0: piv val, 1: rpiv, 2..5: wave partial log sums
//   int   s_i[8]          0: piv idx, 1..4: wave occupancy counts, 4..7: wave neg counts
#define SMEM_BYTES ((NF * STRIDE + NF) * 4 + NF * 4 + 8 * 4 + 8 * 4)

__global__ __launch_bounds__(BLOCK, 2)
void slogdet_lu_kernel(const int* __restrict__ n, const float* __restrict__ M,
                       float* __restrict__ out, int batch, int write_imag)
{
    extern __shared__ char smem_raw[];
    float* At     = (float*)smem_raw;             // NF*STRIDE floats
    float* pivbuf = At + NF * STRIDE;             // NF floats
    int*   R      = (int*)(pivbuf + NF);          // NF ints
    float* s_f    = (float*)(R + NF);             // 8 floats
    int*   s_i    = (int*)(s_f + 8);              // 8 ints

    const int b    = blockIdx.x;
    const int t    = threadIdx.x;
    const int lane = t & 63;
    const int wid  = t >> 6;

    // ---------- R = ascending indices of occupied orbitals ----------
    const int* nrow = n + b * NORB;
    const int occ = (nrow[t] != 0);
    const unsigned long long mask = __ballot(occ);
    const int prefix = __popcll(mask & ((1ULL << lane) - 1ULL));
    if (lane == 0) s_i[1 + wid] = __popcll(mask);
    __syncthreads();
    int offset = 0;
    for (int w = 0; w < wid; ++w) offset += s_i[1 + w];
    if (occ) R[offset + prefix] = t;
    __syncthreads();

    // ---------- gather A[i][j] = M[R[i]*NF + j] into column-major LDS ----------
    for (int idx = t; idx < NF * (NF / 4); idx += BLOCK) {
        const int i  = idx >> 5;      // row 0..127
        const int jv = idx & 31;      // float4 chunk within row
        const float4 v = ((const float4*)(M + R[i] * NF))[jv];
        const int j = jv * 4;
        At[(j + 0) * STRIDE + i] = v.x;
        At[(j + 1) * STRIDE + i] = v.y;
        At[(j + 2) * STRIDE + i] = v.z;
        At[(j + 3) * STRIDE + i] = v.w;
    }
    int swaps = 0;   // meaningful on thread 0 only
    __syncthreads();

    // ---------- LU with partial pivoting ----------
    for (int k = 0; k < NF; ++k) {
        const float* colk = At + k * STRIDE;

        // pivot search over rows k..127 of column k (wave 0)
        if (wid == 0) {
            const int cnt = NF - k;
            unsigned long long best = 0;  // (|v| bits << 32) | row index  (monotone pack)
            if (lane < cnt) {
                const float v = fabsf(colk[k + lane]);
                best = (((unsigned long long)__float_as_uint(v)) << 32) | (unsigned)(k + lane);
            }
            if (lane + 64 < cnt) {
                const float v = fabsf(colk[k + lane + 64]);
                const unsigned long long cand =
                    (((unsigned long long)__float_as_uint(v)) << 32) | (unsigned)(k + lane + 64);
                if (cand > best) best = cand;
            }
            #pragma unroll
            for (int m = 32; m; m >>= 1) {
                const unsigned long long other = __shfl_xor(best, m);
                if (other > best) best = other;
            }
            if (lane == 0) {
                const int p = (int)(best & 0xffffffffu);
                const float pv = colk[p];       // pre-swap position
                s_i[0] = p;
                s_f[0] = pv;
                s_f[1] = 1.0f / pv;
                pivbuf[k] = pv;
                swaps += (p != k);
            }
        }
        __syncthreads();
        const int   p    = s_i[0];
        const float rpiv = s_f[1];

        // swap rows k <-> p across all columns
        if (p != k && t < NF) {
            float* cj = At + t * STRIDE;
            const float a = cj[k];
            const float c = cj[p];
            cj[k] = c;
            cj[p] = a;
        }
        __syncthreads();

        // rank-1 trailing update: A[i][j] -= A[i][k] * (A[k][j] / piv), i>k, j>k
        if (k < NF - 1) {
            const int j = t & 127;
            const int h = t >> 7;
            if (j > k) {
                float* cj = At + j * STRIDE;
                const float uu = cj[k] * rpiv;
                const int mid = (k + 1 + NF) >> 1;
                const int lo = h ? mid : k + 1;
                const int hi = h ? NF : mid;
                int i = lo;
                for (; i < hi && (i & 3); ++i) cj[i] = fmaf(-colk[i], uu, cj[i]);
                for (; i + 3 < hi; i += 4) {
                    float4 a = *(float4*)(cj + i);
                    const float4 l = *(const float4*)(colk + i);
                    a.x = fmaf(-l.x, uu, a.x);
                    a.y = fmaf(-l.y, uu, a.y);
                    a.z = fmaf(-l.z, uu, a.z);
                    a.w = fmaf(-l.w, uu, a.w);
                    *(float4*)(cj + i) = a;
                }
                for (; i < hi; ++i) cj[i] = fmaf(-colk[i], uu, cj[i]);
            }
        }
        __syncthreads();
    }

    // ---------- reduce: logabs = sum log|piv|, sign parity ----------
    float lsum = 0.f;
    int neg = 0;
    if (t < NF) {
        const float v = pivbuf[t];
        lsum = logf(fabsf(v));
        neg = (v < 0.f);
    }
    #pragma unroll
    for (int m = 32; m; m >>= 1) {
        lsum += __shfl_xor(lsum, m);
        neg  += __shfl_xor(neg, m);
    }
    if (lane == 0) { s_f[2 + wid] = lsum; s_i[4 + wid] = neg; }
    __syncthreads();
    if (t == 0) {
        const float total = s_f[2] + s_f[3] + s_f[4] + s_f[5];
        const int negtot  = s_i[4] + s_i[5] + s_i[6] + s_i[7] + swaps;
        // PLANAR complex layout: [batch reals][batch imags]
        out[b] = total;
        if (write_imag) out[batch + b] = (negtot & 1) ? 3.14159265f : 0.f;
    }
}

extern "C" void kernel_launch(void* const* d_in, const int* in_sizes, int n_in,
                              void* d_out, int out_size, void* d_ws, size_t ws_size,
                              hipStream_t stream) {
    const int*   n   = (const int*)d_in[0];     // [B, 256] int32
    const float* M   = (const float*)d_in[1];   // [256, 128] float32
    float*       out = (float*)d_out;

    const int batch = in_sizes[0] / NORB;                 // 4096
    const int write_imag = (out_size >= 2 * batch) ? 1 : 0;

    // >64KB dynamic LDS: opt in (ignore failure; gfx950 has 160KB/CU)
    (void)hipFuncSetAttribute((const void*)slogdet_lu_kernel,
                              hipFuncAttributeMaxDynamicSharedMemorySize,
                              (int)SMEM_BYTES);
    slogdet_lu_kernel<<<batch, BLOCK, SMEM_BYTES, stream>>>(n, M, out, batch, write_imag);
}

// Round 3
// 1452.299 us; speedup vs baseline: 1.2539x; 1.2539x over previous
//
#include <hip/hip_runtime.h>
#include <math.h>

#define NORB 256
#define NF 128
#define BLOCK 64   // one wave per block, one matrix per wave

// Extraction jump table: clo/chi = column kk of the register-resident matrix.
#define EX1(i) case i: clo = rlo[i]; chi = rhi[i]; break;
#define EX8(i) EX1(i) EX1(i+1) EX1(i+2) EX1(i+3) EX1(i+4) EX1(i+5) EX1(i+6) EX1(i+7)

// Full-width rank-1 update; u broadcast from pivot lane via readlane (SGPR operand).
#define UPDATE(SRC) \
  _Pragma("unroll") \
  for (int j = 0; j < 128; ++j) { \
    const float u = __uint_as_float((unsigned)__builtin_amdgcn_readlane( \
        (int)__float_as_uint(SRC[j]), psl)); \
    rlo[j] = fmaf(nlo, u, rlo[j]); \
    rhi[j] = fmaf(nhi, u, rhi[j]); \
  }

__global__ __launch_bounds__(BLOCK, 1)
void slogdet_wave_kernel(const int* __restrict__ n, const float* __restrict__ M,
                         float* __restrict__ out, int batch)
{
    __shared__ int R[NF];       // occupied orbital indices, ascending
    __shared__ int plist[NF];   // pivot physical row per step (for parity)

    const int lane = threadIdx.x;   // 0..63
    const int b    = blockIdx.x;

    // ---------- occupied indices (4 ballot segments of 64 orbitals) ----------
    const unsigned long long lmask_lt = (1ULL << lane) - 1ULL;
    int prevtotal = 0;
    #pragma unroll
    for (int seg = 0; seg < 4; ++seg) {
        const int o = seg * 64 + lane;
        const int occ = (n[b * NORB + o] != 0);
        const unsigned long long m = __ballot(occ);
        const int pre = __popcll(m & lmask_lt);
        if (occ) R[prevtotal + pre] = o;
        prevtotal += __popcll(m);
    }
    __syncthreads();

    // ---------- gather 2 rows per lane into registers ----------
    float rlo[128], rhi[128];
    {
        const float4* m0 = (const float4*)(M + R[lane] * NF);
        const float4* m1 = (const float4*)(M + R[lane + 64] * NF);
        #pragma unroll
        for (int j4 = 0; j4 < 32; ++j4) {
            const float4 v0 = m0[j4];
            rlo[4*j4+0] = v0.x; rlo[4*j4+1] = v0.y; rlo[4*j4+2] = v0.z; rlo[4*j4+3] = v0.w;
            const float4 v1 = m1[j4];
            rhi[4*j4+0] = v1.x; rhi[4*j4+1] = v1.y; rhi[4*j4+2] = v1.z; rhi[4*j4+3] = v1.w;
        }
    }

    float clo = rlo[0], chi = rhi[0];   // current pivot-search column (col 0)
    bool alive_lo = true, alive_hi = true;
    float acc = 0.f;   // sum of log2|pivot|
    int   neg = 0;     // count of negative pivots

    for (int k = 0; k < 128; ++k) {
        // ---- argmax |c| over alive rows (both halves) ----
        const unsigned klo = alive_lo ? __float_as_uint(fabsf(clo)) : 0u;
        const unsigned khi = alive_hi ? __float_as_uint(fabsf(chi)) : 0u;
        unsigned kmax = klo > khi ? klo : khi;
        #pragma unroll
        for (int m = 32; m; m >>= 1) {
            const unsigned o = __shfl_xor(kmax, m);
            kmax = o > kmax ? o : kmax;
        }
        const unsigned long long blo = __ballot(alive_lo && (klo == kmax));
        const unsigned long long bhi = __ballot(alive_hi && (khi == kmax));
        int pl, ishi;
        if (blo) { pl = __ffsll(blo) - 1; ishi = 0; }
        else     { pl = __ffsll(bhi) - 1; ishi = 1; }
        const int p = ishi * 64 + pl;                 // physical row (uniform)
        const float cv = ishi ? chi : clo;
        const float pv = __shfl(cv, pl);              // pivot value (uniform)

        if (lane == 0) plist[k] = p;
        acc += __log2f(fabsf(pv));
        neg += (pv < 0.f) ? 1 : 0;

        // multipliers (frozen rows get 0 -> stay inert forever)
        const float rpiv = 1.0f / pv;
        const float nlo = alive_lo ? -(clo * rpiv) : 0.f;
        const float nhi = alive_hi ? -(chi * rpiv) : 0.f;
        alive_lo = alive_lo && (p != lane);
        alive_hi = alive_hi && (p != 64 + lane);

        if (k == 127) break;

        // ---- rank-1 update, u row broadcast from pivot lane's registers ----
        const int ps  = __builtin_amdgcn_readfirstlane(p);
        const int psl = ps & 63;
        if (ps < 64) { UPDATE(rlo) } else { UPDATE(rhi) }

        // ---- extract next pivot-search column (static-index jump table) ----
        const int kk = k + 1;
        switch (kk) {
            EX8(1)  EX8(9)  EX8(17) EX8(25) EX8(33) EX8(41) EX8(49) EX8(57)
            EX8(65) EX8(73) EX8(81) EX8(89) EX8(97) EX8(105) EX8(113)
            EX1(121) EX1(122) EX1(123) EX1(124) EX1(125) EX1(126) EX1(127)
            default: break;
        }
    }

    // ---------- permutation parity (cycle decomposition, lane 0) ----------
    int par = 0;
    if (lane == 0) {
        unsigned long long vis0 = 0, vis1 = 0;
        int ncyc = 0;
        for (int k = 0; k < 128; ++k) {
            const bool seen = (k < 64) ? ((vis0 >> k) & 1) : ((vis1 >> (k - 64)) & 1);
            if (!seen) {
                ++ncyc;
                int j = k;
                do {
                    if (j < 64) vis0 |= 1ULL << j; else vis1 |= 1ULL << (j - 64);
                    j = plist[j];
                } while (j != k);
            }
        }
        par = (128 - ncyc) & 1;
    }
    par = __builtin_amdgcn_readfirstlane(par);

    if (lane == 0) {
        out[b]         = acc * 0.69314718055994531f;          // log2 -> ln
        out[batch + b] = ((neg + par) & 1) ? 3.14159265358979f : 0.f;
    }
}

extern "C" void kernel_launch(void* const* d_in, const int* in_sizes, int n_in,
                              void* d_out, int out_size, void* d_ws, size_t ws_size,
                              hipStream_t stream) {
    const int*   n   = (const int*)d_in[0];     // [B, 256] int32
    const float* M   = (const float*)d_in[1];   // [256, 128] float32
    float*       out = (float*)d_out;           // planar complex: [B reals][B imags]

    const int batch = in_sizes[0] / NORB;       // 4096
    slogdet_wave_kernel<<<batch, BLOCK, 0, stream>>>(n, M, out, batch);
}